// Round 2
// baseline (73292.169 us; speedup 1.0000x reference)
//
#include <hip/hip_runtime.h>
#include <stdint.h>
#include <stddef.h>

// LSTMNetwork: 3-layer stacked LSTM, batch=1, T=4096, IN=64, H=1024, OUT=1.
//
// Round 10: split completion metadata from data.
//   Round 9 (24.4ms = 5.95us/step) still spent its step period on per-element
//   tag polling: every consumer wave re-read its 2KB row quarter each round
//   (~8 TB/s of LLC probe traffic); store commits queued behind it.
//   New exchange protocol:
//     - Values: packed pure-fp32 rows (2 vals/u64, 4KB per h-row; preacts
//       u32/gate, 16KB/row), read ONCE per step after readiness confirmed.
//     - Readiness: per-producer-block monotone counters, 128 u32 (8 lines)
//       per array. Producer: value stores (relaxed agent) -> __syncthreads
//       (compiler drains vmcnt(0) for ALL waves) -> wave0 release-stores
//       cnt[bu] = t ("steps < t done"). Consumer: wave0 spins on the 128
//       counters (2-4 dword loads/round ~0.5KB, vs 8KB), then barrier, then
//       all waves bulk-load values one-shot.
//   Ordering argument: LLC is the single serialization point; agent-scope
//   atomic loads bypass L1/L2 (proven by rounds 8/9 polls); release publish
//   follows a full store drain, so any value load issued after observing
//   cnt>=t returns final data. Monotone counters also fix replay hygiene:
//   zero_bufs now clears only 2.5KB of counters.
//   Grid 640 @ __launch_bounds__(256,3): all co-resident (<=768).

#define T_STEPS 4096
#define HD      1024
#define NBH     128        // h-blocks (and x-blocks) per layer

typedef unsigned long long u64;
typedef uint32_t u32;

// Module .bss (~176 MB). Harness never pokes these.
__device__ u64 g_valA[(size_t)T_STEPS * 512];   // layer0 h, packed 2fp32/u64 (16MB)
__device__ u64 g_valB[(size_t)T_STEPS * 512];   // layer1 h (16MB)
__device__ u64 g_valC[(size_t)T_STEPS * 512];   // layer2 h (16MB)
__device__ u32 g_pre1[(size_t)T_STEPS * 4096];  // layer1 gate preacts fp32 bits (64MB)
__device__ u32 g_pre2[(size_t)T_STEPS * 4096];  // layer2 gate preacts (64MB)
__device__ u32 g_cnt[5 * NBH];                  // [0..2]*128: cntH L0..L2; [3..4]*128: cntX L1..L2

__device__ __forceinline__ float fsig(float x)  { return 1.0f / (1.0f + __expf(-x)); }
__device__ __forceinline__ float ftanh(float x) { return 1.0f - 2.0f / (__expf(2.0f * x) + 1.0f); }

__global__ __launch_bounds__(640)
void zero_cnt()
{
    const int i = threadIdx.x;
    if (i < 5 * NBH) g_cnt[i] = 0;
}

__global__ __launch_bounds__(256, 3)   // 640 blocks, 3 blocks/CU cap => all co-resident
void fused_scan(const float* __restrict__ seq,
                const float* __restrict__ wih0, const float* __restrict__ whh0_,
                const float* __restrict__ bih0, const float* __restrict__ bhh0,
                const float* __restrict__ wih1, const float* __restrict__ whh1_,
                const float* __restrict__ bih1, const float* __restrict__ bhh1,
                const float* __restrict__ wih2, const float* __restrict__ whh2_,
                const float* __restrict__ bih2, const float* __restrict__ bhh2)
{
    __shared__ float s_buf[2][HD];   // staged source row (own-h for h-role, upstream-h for x-role)

    const int bid  = blockIdx.x;
    const int lane = threadIdx.x & 63;
    const int wave = threadIdx.x >> 6;

    const bool isH  = (bid < 3 * NBH);
    const int layer = isH ? (bid >> 7) : (1 + ((bid - 3 * NBH) >> 7));
    const int bu    = isH ? (bid & (NBH - 1)) : ((bid - 3 * NBH) & (NBH - 1));
    const int j0    = bu * 8 + wave * 2;       // first of this wave's 2 units
    const int k     = lane & 7;                // acc index this lane finalizes (u*4+g)
    const int rk    = ((k & 3) << 10) + j0 + (k >> 2);   // its gate-row in [4H]

    // ---- role pointers ----
    const float* Wmat;
    const u64*  srcVal;
    u64*        valOut = nullptr;
    u32*        preOut = nullptr;
    const u32*  preIn  = nullptr;
    u32*        pubPtr;
    const u32*  pollA;
    const u32*  pollB;
    bool        dual   = false;
    float       biasL  = 0.f;

    if (isH) {
        Wmat   = (layer == 0) ? whh0_ : (layer == 1) ? whh1_ : whh2_;
        valOut = (layer == 0) ? g_valA : (layer == 1) ? g_valB : g_valC;
        srcVal = valOut;                       // own history
        pubPtr = g_cnt + layer * NBH + bu;
        pollA  = g_cnt + layer * NBH;
        pollB  = pollA;
        if (layer >= 1) {
            dual  = true;
            pollB = g_cnt + (3 + layer - 1) * NBH;
            preIn = (layer == 1) ? g_pre1 : g_pre2;
        } else {
            biasL = bih0[rk] + bhh0[rk];
        }
    } else {
        Wmat   = (layer == 1) ? wih1 : wih2;
        srcVal = (layer == 1) ? g_valA : g_valB;
        preOut = (layer == 1) ? g_pre1 : g_pre2;
        pubPtr = g_cnt + (3 + layer - 1) * NBH + bu;
        pollA  = g_cnt + (layer - 1) * NBH;
        pollB  = pollA;
        biasL  = (layer == 1) ? (bih1[rk] + bhh1[rk]) : (bih2[rk] + bhh2[rk]);
    }

    // ---- weights into registers: 8 gate-rows (2 units x 4 gates) x 16 ----
    float W[8][16];
#pragma unroll
    for (int u = 0; u < 2; ++u)
#pragma unroll
        for (int g = 0; g < 4; ++g) {
            const float* pr = Wmat + (size_t)((g << 10) + j0 + u) * HD;
#pragma unroll
            for (int i = 0; i < 16; ++i) W[u * 4 + g][i] = pr[(i << 6) + lane];
        }

    float wi0[8];
    if (isH && layer == 0) {
#pragma unroll
        for (int kk = 0; kk < 8; ++kk)
            wi0[kk] = wih0[(size_t)(((kk & 3) << 10) + j0 + (kk >> 2)) * 64 + lane];
    }

    float c = 0.f;

    for (int t = 0; t < T_STEPS; ++t) {
        const int p = t & 1;

        // ---- (A) drain prev-step value stores (all waves), then publish+poll ----
        __syncthreads();
        if (threadIdx.x == 0)
            __hip_atomic_store(pubPtr, (u32)t, __ATOMIC_RELEASE, __HIP_MEMORY_SCOPE_AGENT);

        if (wave == 0) {
            const u32 nA = isH ? (u32)t : (u32)(t + 1);
            if (dual) {
                const u32 nB = (u32)(t + 1);
                for (;;) {
                    const u32 a0 = __hip_atomic_load(pollA + lane,      __ATOMIC_RELAXED, __HIP_MEMORY_SCOPE_AGENT);
                    const u32 a1 = __hip_atomic_load(pollA + 64 + lane, __ATOMIC_RELAXED, __HIP_MEMORY_SCOPE_AGENT);
                    const u32 b0 = __hip_atomic_load(pollB + lane,      __ATOMIC_RELAXED, __HIP_MEMORY_SCOPE_AGENT);
                    const u32 b1 = __hip_atomic_load(pollB + 64 + lane, __ATOMIC_RELAXED, __HIP_MEMORY_SCOPE_AGENT);
                    if (__all((a0 >= nA) & (a1 >= nA) & (b0 >= nB) & (b1 >= nB))) break;
                }
            } else {
                for (;;) {
                    const u32 a0 = __hip_atomic_load(pollA + lane,      __ATOMIC_RELAXED, __HIP_MEMORY_SCOPE_AGENT);
                    const u32 a1 = __hip_atomic_load(pollA + 64 + lane, __ATOMIC_RELAXED, __HIP_MEMORY_SCOPE_AGENT);
                    if (__all((a0 >= nA) & (a1 >= nA))) break;
                }
            }
        }
        __syncthreads();   // (B) readiness visible to all waves

        // ---- one-shot staging (no retries) ----
        if (!isH || t > 0) {
            const size_t row = (size_t)(isH ? (t - 1) : t) * 512;
            const int d0 = (wave << 7) + lane;
            const u64 q0 = __hip_atomic_load(srcVal + row + d0,      __ATOMIC_RELAXED, __HIP_MEMORY_SCOPE_AGENT);
            const u64 q1 = __hip_atomic_load(srcVal + row + d0 + 64, __ATOMIC_RELAXED, __HIP_MEMORY_SCOPE_AGENT);
            float2* sp2 = reinterpret_cast<float2*>(&s_buf[p][0]);
            sp2[d0]      = make_float2(__uint_as_float((u32)q0), __uint_as_float((u32)(q0 >> 32)));
            sp2[d0 + 64] = make_float2(__uint_as_float((u32)q1), __uint_as_float((u32)(q1 >> 32)));
        }
        float preF = 0.f, xv = 0.f;
        if (isH) {
            if (layer == 0) {
                xv = seq[(size_t)t * 64 + lane];
            } else {
                preF = __uint_as_float(
                    __hip_atomic_load(preIn + (size_t)t * 4096 + (j0 << 2) + k,
                                      __ATOMIC_RELAXED, __HIP_MEMORY_SCOPE_AGENT));
            }
        }
        __syncthreads();   // (C) LDS row staged

        // ---- 8 gate dot-products (per-lane partials) ----
        float a0, a1, a2, a3, a4, a5, a6, a7;
        if (isH && layer == 0) {
            a0 = wi0[0] * xv; a1 = wi0[1] * xv; a2 = wi0[2] * xv; a3 = wi0[3] * xv;
            a4 = wi0[4] * xv; a5 = wi0[5] * xv; a6 = wi0[6] * xv; a7 = wi0[7] * xv;
        } else {
            a0 = a1 = a2 = a3 = a4 = a5 = a6 = a7 = 0.f;
        }
        if (!isH || t > 0) {
            const float* sp = s_buf[p];
#pragma unroll
            for (int i = 0; i < 16; ++i) {
                const float hv = sp[(i << 6) | lane];
                a0 = __fmaf_rn(W[0][i], hv, a0);
                a1 = __fmaf_rn(W[1][i], hv, a1);
                a2 = __fmaf_rn(W[2][i], hv, a2);
                a3 = __fmaf_rn(W[3][i], hv, a3);
                a4 = __fmaf_rn(W[4][i], hv, a4);
                a5 = __fmaf_rn(W[5][i], hv, a5);
                a6 = __fmaf_rn(W[6][i], hv, a6);
                a7 = __fmaf_rn(W[7][i], hv, a7);
            }
        }

        // ---- scatter-butterfly reduce: lane l ends with 64-lane sum of acc (l&7) ----
        float e;
        {
            const int l1 = lane & 1, l2 = lane & 2, l4 = lane & 4;
            const float s0 = __shfl_xor(a0, 1, 64), s1 = __shfl_xor(a1, 1, 64);
            const float s2 = __shfl_xor(a2, 1, 64), s3 = __shfl_xor(a3, 1, 64);
            const float s4 = __shfl_xor(a4, 1, 64), s5 = __shfl_xor(a5, 1, 64);
            const float s6 = __shfl_xor(a6, 1, 64), s7 = __shfl_xor(a7, 1, 64);
            const float c0 = l1 ? (a1 + s1) : (a0 + s0);
            const float c1 = l1 ? (a3 + s3) : (a2 + s2);
            const float c2 = l1 ? (a5 + s5) : (a4 + s4);
            const float c3 = l1 ? (a7 + s7) : (a6 + s6);
            const float u0 = __shfl_xor(c0, 2, 64), u1 = __shfl_xor(c1, 2, 64);
            const float u2 = __shfl_xor(c2, 2, 64), u3 = __shfl_xor(c3, 2, 64);
            const float d0 = l2 ? (c1 + u1) : (c0 + u0);
            const float d1 = l2 ? (c3 + u3) : (c2 + u2);
            const float v0 = __shfl_xor(d0, 4, 64), v1 = __shfl_xor(d1, 4, 64);
            e = l4 ? (d1 + v1) : (d0 + v0);
            e += __shfl_xor(e, 8, 64);
            e += __shfl_xor(e, 16, 64);
            e += __shfl_xor(e, 32, 64);
        }

        // ---- epilogue ----
        if (isH) {
            const float val = e + ((layer == 0) ? biasL : preF);
            // gate nonlinearity: k&3 == 2 is the g-gate (tanh), others sigmoid
            const float av = ((lane & 3) == 2) ? ftanh(val) : fsig(val);
            const int gb = lane & ~3;
            const float iv = __shfl(av, gb + 0, 64);
            const float fv = __shfl(av, gb + 1, 64);
            const float gv = __shfl(av, gb + 2, 64);
            const float ov = __shfl(av, gb + 3, 64);
            c = __fmaf_rn(fv, c, iv * gv);
            const float h = ov * ftanh(c);
            const float hHi = __shfl(h, 4, 64);   // lane 4 holds h for unit j0+1
            if (lane == 0) {
                const u64 pk = ((u64)__float_as_uint(hHi) << 32) | (u64)__float_as_uint(h);
                __hip_atomic_store(valOut + (size_t)t * 512 + ((bu << 2) + wave), pk,
                                   __ATOMIC_RELAXED, __HIP_MEMORY_SCOPE_AGENT);
            }
        } else {
            const float val = e + biasL;          // preact carries Wih.x + b_ih + b_hh
            if (lane < 8)
                __hip_atomic_store(preOut + (size_t)t * 4096 + (j0 << 2) + lane,
                                   __float_as_uint(val),
                                   __ATOMIC_RELAXED, __HIP_MEMORY_SCOPE_AGENT);
        }
    }

    // final publish (x: preact 4095 ready; h L0/L1: row 4095 ready for x-consumers)
    __syncthreads();
    if (threadIdx.x == 0)
        __hip_atomic_store(pubPtr, (u32)T_STEPS, __ATOMIC_RELEASE, __HIP_MEMORY_SCOPE_AGENT);
}

__global__ __launch_bounds__(256)
void final_kernel(const float* __restrict__ w_lin,
                  const float* __restrict__ b_lin,
                  float*       __restrict__ out)
{
    __shared__ float red[256];
    const int tid = threadIdx.x;
    const u64* vrow = g_valC + (size_t)(T_STEPS - 1) * 512;
    float s = 0.f;
#pragma unroll
    for (int i = 0; i < 2; ++i) {
        const int d = tid * 2 + i;               // u64 index 0..511 -> units 2d, 2d+1
        const u64 q = vrow[d];
        s += __uint_as_float((u32)q)         * w_lin[2 * d]
           + __uint_as_float((u32)(q >> 32)) * w_lin[2 * d + 1];
    }
    red[tid] = s;
    __syncthreads();
    for (int o = 128; o > 0; o >>= 1) {
        if (tid < o) red[tid] += red[tid + o];
        __syncthreads();
    }
    if (tid == 0) out[0] = red[0] + b_lin[0];
}

extern "C" void kernel_launch(void* const* d_in, const int* in_sizes, int n_in,
                              void* d_out, int out_size, void* d_ws, size_t ws_size,
                              hipStream_t stream)
{
    (void)in_sizes; (void)n_in; (void)out_size; (void)d_ws; (void)ws_size;

    const float* seq   = (const float*)d_in[0];
    const float* w_ih0 = (const float*)d_in[1];
    const float* w_hh0 = (const float*)d_in[2];
    const float* b_ih0 = (const float*)d_in[3];
    const float* b_hh0 = (const float*)d_in[4];
    const float* w_ih1 = (const float*)d_in[5];
    const float* w_hh1 = (const float*)d_in[6];
    const float* b_ih1 = (const float*)d_in[7];
    const float* b_hh1 = (const float*)d_in[8];
    const float* w_ih2 = (const float*)d_in[9];
    const float* w_hh2 = (const float*)d_in[10];
    const float* b_ih2 = (const float*)d_in[11];
    const float* b_hh2 = (const float*)d_in[12];
    const float* w_lin = (const float*)d_in[13];
    const float* b_lin = (const float*)d_in[14];

    // Replay hygiene: monotone counters must restart at 0 each launch.
    zero_cnt<<<dim3(1), dim3(640), 0, stream>>>();

    // Blocks [0,384) = h-role (128/layer); [384,640) = x-role (128 for L1, 128 for L2).
    fused_scan<<<dim3(640), dim3(256), 0, stream>>>(
        seq,
        w_ih0, w_hh0, b_ih0, b_hh0,
        w_ih1, w_hh1, b_ih1, b_hh1,
        w_ih2, w_hh2, b_ih2, b_hh2);

    final_kernel<<<dim3(1), dim3(256), 0, stream>>>(w_lin, b_lin, (float*)d_out);
}

// Round 3
// 25775.717 us; speedup vs baseline: 2.8435x; 2.8435x over previous
//
#include <hip/hip_runtime.h>
#include <stdint.h>
#include <stddef.h>

// LSTMNetwork: 3-layer stacked LSTM, batch=1, T=4096, IN=64, H=1024, OUT=1.
//
// Round 11: revert to round-9 protocol (self-validating slots, zero fences,
// incremental staging) and halve its probe traffic.
//   Round 10's counter+release scheme regressed 3x: agent-scope RELEASE
//   fences (L2 writeback) per step per block, a serialized counter->data
//   two-hop chain, and loss of straggler/staging overlap. Reverted.
//   Round 9's limiter was LLC probe bandwidth (~640 blocks x 8KB/round of
//   u64 [tag|val] slots ~ 5+ TB/s of LLC reads -> queueing inflates the
//   store->load visibility latency that sets the 5.95us step period).
//   Change: slots are now u32 = fp32 value with mantissa LSB as validity
//   bit (stored bits &~1, init pattern 0x1). All exchange buffers are
//   write-once full histories (incl. layer-2 h), so LSB==0 <=> written is
//   unconditionally sound: no phases, no counters, no fences. Probe bytes,
//   staged bytes, and line count all halve; protocol otherwise identical.
//   Numerics: <=2^-23 relative perturbation per stored value, contracting
//   through LSTM gates.
//   Grid 640 @ __launch_bounds__(256,3): all co-resident (proven r9/r10).

#define T_STEPS 4096
#define HD      1024
#define NBH     128        // h-blocks (and x-blocks) per layer

typedef unsigned long long u64;
typedef uint32_t u32;

// Module .bss (~176 MB). Harness never pokes these.
__device__ u32 g_valA[(size_t)T_STEPS * HD];    // layer0 h history (16MB)
__device__ u32 g_valB[(size_t)T_STEPS * HD];    // layer1 h history (16MB)
__device__ u32 g_valC[(size_t)T_STEPS * HD];    // layer2 h history (16MB)
__device__ u32 g_pre1[(size_t)T_STEPS * 4096];  // layer1 gate preacts (64MB)
__device__ u32 g_pre2[(size_t)T_STEPS * 4096];  // layer2 gate preacts (64MB)

__device__ __forceinline__ float fsig(float x)  { return 1.0f / (1.0f + __expf(-x)); }
__device__ __forceinline__ float ftanh(float x) { return 1.0f - 2.0f / (__expf(2.0f * x) + 1.0f); }

__global__ __launch_bounds__(256)
void init_bufs()
{
    const size_t gtid = (size_t)blockIdx.x * blockDim.x + threadIdx.x;
    const size_t step = (size_t)gridDim.x * blockDim.x;
    const size_t nh = (size_t)T_STEPS * HD;
    const size_t np = (size_t)T_STEPS * 4096;
    for (size_t i = gtid; i < nh; i += step) { g_valA[i] = 1u; g_valB[i] = 1u; g_valC[i] = 1u; }
    for (size_t i = gtid; i < np; i += step) { g_pre1[i] = 1u; g_pre2[i] = 1u; }
}

__global__ __launch_bounds__(256, 3)   // 640 blocks, 3 blocks/CU cap => all co-resident
void fused_scan(const float* __restrict__ seq,
                const float* __restrict__ wih0, const float* __restrict__ whh0_,
                const float* __restrict__ bih0, const float* __restrict__ bhh0,
                const float* __restrict__ wih1, const float* __restrict__ whh1_,
                const float* __restrict__ bih1, const float* __restrict__ bhh1,
                const float* __restrict__ wih2, const float* __restrict__ whh2_,
                const float* __restrict__ bih2, const float* __restrict__ bhh2)
{
    __shared__ float s_buf[2][HD];   // staged source row (own-h for h-role, upstream-h for x-role)

    const int bid  = blockIdx.x;
    const int lane = threadIdx.x & 63;
    const int wave = threadIdx.x >> 6;

    const bool isH  = (bid < 3 * NBH);
    const int layer = isH ? (bid >> 7) : (1 + ((bid - 3 * NBH) >> 7));
    const int bu    = isH ? (bid & (NBH - 1)) : ((bid - 3 * NBH) & (NBH - 1));
    const int j0    = bu * 8 + wave * 2;       // first of this wave's 2 units
    const int k     = lane & 7;                // acc index this lane finalizes (u*4+g)
    const int rk    = ((k & 3) << 10) + j0 + (k >> 2);   // its gate-row in [4H]

    // ---- role pointers ----
    const float* Wmat;
    const u32*  srcVal;
    u32*        valOut = nullptr;
    u32*        preOut = nullptr;
    const u32*  preIn  = nullptr;
    float       biasL  = 0.f;

    if (isH) {
        Wmat   = (layer == 0) ? whh0_ : (layer == 1) ? whh1_ : whh2_;
        valOut = (layer == 0) ? g_valA : (layer == 1) ? g_valB : g_valC;
        srcVal = valOut;                       // own history
        if (layer == 1) preIn = g_pre1;
        if (layer == 2) preIn = g_pre2;
        if (layer == 0) biasL = bih0[rk] + bhh0[rk];
    } else {
        Wmat   = (layer == 1) ? wih1 : wih2;
        srcVal = (layer == 1) ? g_valA : g_valB;
        preOut = (layer == 1) ? g_pre1 : g_pre2;
        biasL  = (layer == 1) ? (bih1[rk] + bhh1[rk]) : (bih2[rk] + bhh2[rk]);
    }

    // ---- weights into registers: 8 gate-rows (2 units x 4 gates) x 16 ----
    float W[8][16];
#pragma unroll
    for (int u = 0; u < 2; ++u)
#pragma unroll
        for (int g = 0; g < 4; ++g) {
            const float* pr = Wmat + (size_t)((g << 10) + j0 + u) * HD;
#pragma unroll
            for (int i = 0; i < 16; ++i) W[u * 4 + g][i] = pr[(i << 6) + lane];
        }

    float wi0[8];
    if (isH && layer == 0) {
#pragma unroll
        for (int kk = 0; kk < 8; ++kk)
            wi0[kk] = wih0[(size_t)(((kk & 3) << 10) + j0 + (kk >> 2)) * 64 + lane];
    }

    float c = 0.f;
    const int sb = wave << 8;    // this wave's staging quarter [sb, sb+256)

    for (int t = 0; t < T_STEPS; ++t) {
        const int p = t & 1;
        u32 preBits = 1u; float xv = 0.f;
        const bool needRow = (!isH) || (t > 0);

        // ---- early preact probe (one 32B sub-line, >=1 pipeline slot of slack) ----
        if (isH) {
            if (layer == 0) {
                xv = seq[(size_t)t * 64 + lane];
            } else {
                preBits = __hip_atomic_load(preIn + (size_t)t * 4096 + (j0 << 2) + k,
                                            __ATOMIC_RELAXED, __HIP_MEMORY_SCOPE_AGENT);
            }
        }

        // ---- staging: poll own quarter of source row, stage incrementally ----
        if (needRow) {
            const u32* rowp = srcVal + (size_t)(isH ? (t - 1) : t) * HD;
            u32 todo = 0xFu;
            while (__any(todo)) {
#pragma unroll
                for (int i = 0; i < 4; ++i) if (todo & (1u << i)) {
                    const u32 v = __hip_atomic_load(rowp + sb + (i << 6) + lane,
                                                    __ATOMIC_RELAXED, __HIP_MEMORY_SCOPE_AGENT);
                    if (!(v & 1u)) {
                        s_buf[p][sb + (i << 6) + lane] = __uint_as_float(v);
                        todo &= ~(1u << i);
                    }
                }
            }
        }
        __syncthreads();

        // ---- 8 gate dot-products (per-lane partials) ----
        float a0, a1, a2, a3, a4, a5, a6, a7;
        if (isH && layer == 0) {
            a0 = wi0[0] * xv; a1 = wi0[1] * xv; a2 = wi0[2] * xv; a3 = wi0[3] * xv;
            a4 = wi0[4] * xv; a5 = wi0[5] * xv; a6 = wi0[6] * xv; a7 = wi0[7] * xv;
        } else {
            a0 = a1 = a2 = a3 = a4 = a5 = a6 = a7 = 0.f;
        }
        if (needRow) {
            const float* sp = s_buf[p];
#pragma unroll
            for (int i = 0; i < 16; ++i) {
                const float hv = sp[(i << 6) | lane];
                a0 = __fmaf_rn(W[0][i], hv, a0);
                a1 = __fmaf_rn(W[1][i], hv, a1);
                a2 = __fmaf_rn(W[2][i], hv, a2);
                a3 = __fmaf_rn(W[3][i], hv, a3);
                a4 = __fmaf_rn(W[4][i], hv, a4);
                a5 = __fmaf_rn(W[5][i], hv, a5);
                a6 = __fmaf_rn(W[6][i], hv, a6);
                a7 = __fmaf_rn(W[7][i], hv, a7);
            }
        }

        // ---- scatter-butterfly reduce: lane l ends with 64-lane sum of acc (l&7) ----
        float e;
        {
            const int l1 = lane & 1, l2 = lane & 2, l4 = lane & 4;
            const float s0 = __shfl_xor(a0, 1, 64), s1 = __shfl_xor(a1, 1, 64);
            const float s2 = __shfl_xor(a2, 1, 64), s3 = __shfl_xor(a3, 1, 64);
            const float s4 = __shfl_xor(a4, 1, 64), s5 = __shfl_xor(a5, 1, 64);
            const float s6 = __shfl_xor(a6, 1, 64), s7 = __shfl_xor(a7, 1, 64);
            const float c0 = l1 ? (a1 + s1) : (a0 + s0);
            const float c1 = l1 ? (a3 + s3) : (a2 + s2);
            const float c2 = l1 ? (a5 + s5) : (a4 + s4);
            const float c3 = l1 ? (a7 + s7) : (a6 + s6);
            const float u0 = __shfl_xor(c0, 2, 64), u1 = __shfl_xor(c1, 2, 64);
            const float u2 = __shfl_xor(c2, 2, 64), u3 = __shfl_xor(c3, 2, 64);
            const float d0 = l2 ? (c1 + u1) : (c0 + u0);
            const float d1 = l2 ? (c3 + u3) : (c2 + u2);
            const float v0 = __shfl_xor(d0, 4, 64), v1 = __shfl_xor(d1, 4, 64);
            e = l4 ? (d1 + v1) : (d0 + v0);
            e += __shfl_xor(e, 8, 64);
            e += __shfl_xor(e, 16, 64);
            e += __shfl_xor(e, 32, 64);
        }

        // ---- epilogue ----
        if (isH) {
            float add;
            if (layer == 0) {
                add = biasL;
            } else {
                while (__any(preBits & 1u)) {
                    if (preBits & 1u)
                        preBits = __hip_atomic_load(preIn + (size_t)t * 4096 + (j0 << 2) + k,
                                                    __ATOMIC_RELAXED, __HIP_MEMORY_SCOPE_AGENT);
                }
                add = __uint_as_float(preBits);   // preact carries Wih.x + b_ih + b_hh
            }
            const float val = e + add;
            // gate nonlinearity: k&3 == 2 is the g-gate (tanh), others sigmoid
            const float av = ((lane & 3) == 2) ? ftanh(val) : fsig(val);
            const int gb = lane & ~3;
            const float iv = __shfl(av, gb + 0, 64);
            const float fv = __shfl(av, gb + 1, 64);
            const float gv = __shfl(av, gb + 2, 64);
            const float ov = __shfl(av, gb + 3, 64);
            c = __fmaf_rn(fv, c, iv * gv);
            const float h = ov * ftanh(c);
            if (lane == 0 || lane == 4) {
                __hip_atomic_store(valOut + (size_t)t * HD + j0 + (lane >> 2),
                                   __float_as_uint(h) & ~1u,
                                   __ATOMIC_RELAXED, __HIP_MEMORY_SCOPE_AGENT);
            }
        } else {
            const float val = e + biasL;
            if (lane < 8)
                __hip_atomic_store(preOut + (size_t)t * 4096 + (j0 << 2) + lane,
                                   __float_as_uint(val) & ~1u,
                                   __ATOMIC_RELAXED, __HIP_MEMORY_SCOPE_AGENT);
        }
    }
}

__global__ __launch_bounds__(256)
void final_kernel(const float* __restrict__ w_lin,
                  const float* __restrict__ b_lin,
                  float*       __restrict__ out)
{
    __shared__ float red[256];
    const int tid = threadIdx.x;
    const u32* vrow = g_valC + (size_t)(T_STEPS - 1) * HD;
    float s = 0.f;
#pragma unroll
    for (int i = 0; i < 4; ++i) {
        const int kk = tid + 256 * i;
        s += __uint_as_float(vrow[kk]) * w_lin[kk];
    }
    red[tid] = s;
    __syncthreads();
    for (int o = 128; o > 0; o >>= 1) {
        if (tid < o) red[tid] += red[tid + o];
        __syncthreads();
    }
    if (tid == 0) out[0] = red[0] + b_lin[0];
}

extern "C" void kernel_launch(void* const* d_in, const int* in_sizes, int n_in,
                              void* d_out, int out_size, void* d_ws, size_t ws_size,
                              hipStream_t stream)
{
    (void)in_sizes; (void)n_in; (void)out_size; (void)d_ws; (void)ws_size;

    const float* seq   = (const float*)d_in[0];
    const float* w_ih0 = (const float*)d_in[1];
    const float* w_hh0 = (const float*)d_in[2];
    const float* b_ih0 = (const float*)d_in[3];
    const float* b_hh0 = (const float*)d_in[4];
    const float* w_ih1 = (const float*)d_in[5];
    const float* w_hh1 = (const float*)d_in[6];
    const float* b_ih1 = (const float*)d_in[7];
    const float* b_hh1 = (const float*)d_in[8];
    const float* w_ih2 = (const float*)d_in[9];
    const float* w_hh2 = (const float*)d_in[10];
    const float* b_ih2 = (const float*)d_in[11];
    const float* b_hh2 = (const float*)d_in[12];
    const float* w_lin = (const float*)d_in[13];
    const float* b_lin = (const float*)d_in[14];

    // Replay hygiene: all slots back to "unwritten" (LSB=1) each launch.
    init_bufs<<<dim3(2048), dim3(256), 0, stream>>>();

    // Blocks [0,384) = h-role (128/layer); [384,640) = x-role (128 for L1, 128 for L2).
    fused_scan<<<dim3(640), dim3(256), 0, stream>>>(
        seq,
        w_ih0, w_hh0, b_ih0, b_hh0,
        w_ih1, w_hh1, b_ih1, b_hh1,
        w_ih2, w_hh2, b_ih2, b_hh2);

    final_kernel<<<dim3(1), dim3(256), 0, stream>>>(w_lin, b_lin, (float*)d_out);
}